// Round 1
// baseline (841.254 us; speedup 1.0000x reference)
//
#include <hip/hip_runtime.h>
#include <hip/hip_bf16.h>
#include <math.h>

#define NPTS 8192
#define BN_TOT 16384
#define ROWS_TOT 262144
#define STAT_CNT 262144.0f
#define BN_EPS 1e-5f

typedef __attribute__((__ext_vector_type__(8))) __bf16 bf16x8;
typedef __attribute__((__ext_vector_type__(4))) float f32x4;

// stats region float offsets
#define SD_SUM 0
#define SD_SSQ 4
#define SG1_SUM 8
#define SG1_SSQ 136
#define SG2_SUM 264
#define SG2_SSQ 392
#define SD_SC 520
#define SD_SH 524
#define SG1_SC 528
#define SG1_SH 656
#define SG2_SC 784
#define SG2_SH 912
#define STATS_FLOATS 1040

__device__ __forceinline__ unsigned short f2b(float x){
  unsigned u = __float_as_uint(x);
  return (unsigned short)((u + 0x7FFFu + ((u>>16)&1u)) >> 16);
}
__device__ __forceinline__ float b2f(unsigned short h){
  return __uint_as_float(((unsigned)h)<<16);
}
__device__ __forceinline__ float gelu_f(float x){
  return 0.5f*x*(1.0f + erff(x*0.70710678118654752440f));
}
// XOR-swizzled LDS addressing for [128 rows][256B] bf16 tiles (G4 fix)
__device__ __forceinline__ int swz(int row, int byteInRow){
  return row*256 + (byteInRow ^ ((row&7)<<4));
}

#define MFMA16(a,b,c) __builtin_amdgcn_mfma_f32_16x16x32_bf16((a),(b),(c),0,0,0)

__device__ __forceinline__ bf16x8 ldsA8(const unsigned short* sA, int row, int k){
  return *(const bf16x8*)((const char*)sA + swz(row, k*2));
}
__device__ __forceinline__ bf16x8 ldW8(const unsigned short* W, int n, int k){
  return *(const bf16x8*)(W + n*128 + k);
}

// wave computes rows [row0,row0+32) x 128 cols; A in swizzled LDS, W bf16 [128][128] row-major
__device__ __forceinline__ void gemm32(f32x4 acc[2][8], const unsigned short* sA,
                                       const unsigned short* W, int row0, int lane){
  int r = lane & 15, g = lane >> 4;
  #pragma unroll
  for (int ks=0; ks<4; ++ks){
    int k = ks*32 + g*8;
    bf16x8 a0 = ldsA8(sA, row0 + r, k);
    bf16x8 a1 = ldsA8(sA, row0 + 16 + r, k);
    #pragma unroll
    for (int nt=0; nt<8; ++nt){
      bf16x8 b = ldW8(W, nt*16 + r, k);
      acc[0][nt] = MFMA16(a0, b, acc[0][nt]);
      acc[1][nt] = MFMA16(a1, b, acc[1][nt]);
    }
  }
}

// unsorted top-16 (smallest) with tracked max slot; all static indices (rule #20)
__device__ __forceinline__ void ins16(float d, int ii, float td[16], int ti[16], float& maxv, int& maxp){
  bool iv = d < maxv;
  #pragma unroll
  for (int j=0;j<16;j++){
    bool sel = iv && (j==maxp);
    td[j] = sel ? d : td[j];
    ti[j] = sel ? ii : ti[j];
  }
  float mv = td[0]; int mp = 0;
  #pragma unroll
  for (int j=1;j<16;j++){
    bool gt = td[j] > mv;
    mv = gt ? td[j] : mv;
    mp = gt ? j : mp;
  }
  maxv = mv; maxp = mp;
}

__global__ __launch_bounds__(256) void k_prep(
    const float* __restrict__ feats, const float* __restrict__ Wq, const float* __restrict__ Wk,
    const float* __restrict__ Wv, const float* __restrict__ Wg1, const float* __restrict__ Wg2,
    unsigned short* __restrict__ wbf, unsigned short* __restrict__ featb, float* __restrict__ stats)
{
  int i = blockIdx.x*256 + threadIdx.x;   // grid covers exactly 2097152
  featb[i] = f2b(feats[i]);
  if (i < 16384){
    wbf[i]        = f2b(Wq[i]);
    wbf[16384+i]  = f2b(Wk[i]);
    wbf[32768+i]  = f2b(Wv[i]);
    wbf[49152+i]  = f2b(Wg1[i]);
    wbf[65536+i]  = f2b(Wg2[i]);
  }
  if (i < STATS_FLOATS) stats[i] = 0.f;
}

// thread-per-query over a 2048-candidate chunk; buffered inserts for wave coherence
__global__ __launch_bounds__(256) void k_knn(const float* __restrict__ points, float2* __restrict__ pairs){
  __shared__ float4 cpts[2048];
  int blk = blockIdx.x;
  int chunk = blk >> 6;          // 4 chunks
  int qblk = blk & 63;
  int qi = qblk*256 + threadIdx.x;
  int b = qi >> 13;
  int cbase = b*NPTS + chunk*2048;
  for (int t = threadIdx.x; t < 2048; t += 256){
    const float* p = points + (size_t)(cbase + t)*3;
    float x=p[0], y=p[1], z=p[2];
    cpts[t] = make_float4(x,y,z, fmaf(z,z,fmaf(y,y,x*x)));
  }
  __syncthreads();
  const float* qp = points + (size_t)qi*3;
  float qx=qp[0], qy=qp[1], qz=qp[2];
  float qpn = fmaf(qz,qz,fmaf(qy,qy,qx*qx));
  float td[16]; int ti[16];
  #pragma unroll
  for (int j=0;j<16;j++){ td[j]=3.4e38f; ti[j]=0; }
  float maxv=3.4e38f; int maxp=0;
  float pd[4]={0,0,0,0}; int pix[4]={0,0,0,0}; int pcnt=0;
  for (int cc=0; cc<2048; ++cc){
    float4 cp = cpts[cc];
    float d2 = (qpn + cp.w) - 2.0f*fmaf(qx,cp.x,fmaf(qy,cp.y,qz*cp.z));
    if (d2 < maxv){
      pd[0]=(pcnt==0)?d2:pd[0]; pix[0]=(pcnt==0)?cc:pix[0];
      pd[1]=(pcnt==1)?d2:pd[1]; pix[1]=(pcnt==1)?cc:pix[1];
      pd[2]=(pcnt==2)?d2:pd[2]; pix[2]=(pcnt==2)?cc:pix[2];
      pd[3]=(pcnt==3)?d2:pd[3]; pix[3]=(pcnt==3)?cc:pix[3];
      pcnt++;
    }
    if (__any(pcnt==4)){
      #pragma unroll
      for (int t=0;t<4;t++){
        float d = (t<pcnt)? pd[t] : 3.0e38f;   // sentinels get evicted by real values
        ins16(d, chunk*2048 + pix[t], td, ti, maxv, maxp);
      }
      pcnt=0;
    }
  }
  #pragma unroll
  for (int t=0;t<4;t++){
    float d = (t<pcnt)? pd[t] : 3.0e38f;
    ins16(d, chunk*2048 + pix[t], td, ti, maxv, maxp);
  }
  float2* op = pairs + ((size_t)qi*4 + chunk)*16;
  #pragma unroll
  for (int j=0;j<16;j++) op[j] = make_float2(td[j], __int_as_float(ti[j]));
}

__global__ __launch_bounds__(256) void k_merge(const float2* __restrict__ pairs, int* __restrict__ idxb,
    const float* __restrict__ points, const float* __restrict__ Wd1, const float* __restrict__ bd1,
    float* __restrict__ stats){
  __shared__ float sS[6];
  if (threadIdx.x < 6) sS[threadIdx.x]=0.f;
  __syncthreads();
  int qi = blockIdx.x*256 + threadIdx.x;
  float td[16]; int ti[16];
  #pragma unroll
  for (int j=0;j<16;j++){ td[j]=3.4e38f; ti[j]=0; }
  float maxv=3.4e38f; int maxp=0;
  const float2* pp = pairs + (size_t)qi*64;
  for (int j=0;j<64;++j){
    float d = pp[j].x;
    int ii = __float_as_int(pp[j].y);
    if (d < maxv) ins16(d, ii, td, ti, maxv, maxp);
  }
  #pragma unroll
  for (int j=0;j<16;j++) idxb[(size_t)qi*16+j] = ti[j];
  // BN-d statistics over pos1 = Wd1*(q - nbr) + bd1
  int b = qi >> 13;
  const float* qp = points + (size_t)qi*3;
  float qx=qp[0],qy=qp[1],qz=qp[2];
  float w00=Wd1[0],w01=Wd1[1],w02=Wd1[2],w10=Wd1[3],w11=Wd1[4],w12=Wd1[5],w20=Wd1[6],w21=Wd1[7],w22=Wd1[8];
  float b0=bd1[0],b1=bd1[1],b2=bd1[2];
  float s0=0,s1=0,s2=0,q0=0,q1=0,q2=0;
  #pragma unroll
  for (int j=0;j<16;j++){
    const float* np_ = points + (size_t)(b*NPTS + ti[j])*3;
    float dx=qx-np_[0], dy=qy-np_[1], dz=qz-np_[2];
    float t0 = fmaf(dz,w02,fmaf(dy,w01,dx*w00)) + b0;
    float t1 = fmaf(dz,w12,fmaf(dy,w11,dx*w10)) + b1;
    float t2 = fmaf(dz,w22,fmaf(dy,w21,dx*w20)) + b2;
    s0+=t0; s1+=t1; s2+=t2;
    q0=fmaf(t0,t0,q0); q1=fmaf(t1,t1,q1); q2=fmaf(t2,t2,q2);
  }
  atomicAdd(&sS[0],s0); atomicAdd(&sS[1],s1); atomicAdd(&sS[2],s2);
  atomicAdd(&sS[3],q0); atomicAdd(&sS[4],q1); atomicAdd(&sS[5],q2);
  __syncthreads();
  if (threadIdx.x < 3) atomicAdd(&stats[SD_SUM+threadIdx.x], sS[threadIdx.x]);
  else if (threadIdx.x < 6) atomicAdd(&stats[SD_SSQ+threadIdx.x-3], sS[threadIdx.x]);
}

__global__ void k_finalize(float* stats, int sumOff, int ssqOff, const float* __restrict__ gm,
                           const float* __restrict__ bt, int scOff, int shOff, int C){
  int c = blockIdx.x*64 + threadIdx.x;
  if (c >= C) return;
  float m = stats[sumOff+c] * (1.0f/STAT_CNT);
  float v = stats[ssqOff+c] * (1.0f/STAT_CNT) - m*m;
  v = fmaxf(v, 0.0f);
  float rs = rsqrtf(v + BN_EPS);
  float sc = gm[c]*rs;
  stats[scOff+c] = sc;
  stats[shOff+c] = fmaf(-m, sc, bt[c]);
}

__global__ __launch_bounds__(256) void k_q(const unsigned short* __restrict__ featb,
    const unsigned short* __restrict__ W, const float* __restrict__ bq, float* __restrict__ qout)
{
  __shared__ __align__(16) unsigned short sA[128*128];
  int tid=threadIdx.x;
  size_t row0=(size_t)blockIdx.x*128;
  for (int t=tid;t<2048;t+=256){
    int row=t>>4,c=t&15;
    uint4 v = *(const uint4*)(featb + (row0+row)*128 + c*8);
    *(uint4*)((char*)sA + swz(row,c*16)) = v;
  }
  __syncthreads();
  int wid=tid>>6, lane=tid&63;
  int r=lane&15, g=lane>>4;
  f32x4 acc[2][8] = {};
  gemm32(acc, sA, W, wid*32, lane);
  #pragma unroll
  for (int nt=0;nt<8;++nt){
    int ch=nt*16+r; float bc=bq[ch];
    #pragma unroll
    for (int mt=0;mt<2;++mt){
      #pragma unroll
      for (int rr=0;rr<4;++rr){
        int row=wid*32+mt*16+g*4+rr;
        qout[(row0+row)*128+ch] = acc[mt][nt][rr] + bc;
      }
    }
  }
}

__global__ __launch_bounds__(256) void k_main(
    const float* __restrict__ points, const unsigned short* __restrict__ featb,
    const unsigned short* __restrict__ wbf,
    const float* __restrict__ bk, const float* __restrict__ bv,
    const float* __restrict__ Wd1, const float* __restrict__ bd1,
    const float* __restrict__ Wd2, const float* __restrict__ bd2,
    const int* __restrict__ idxb, const float* __restrict__ qbuf,
    float* __restrict__ stats,
    unsigned short* __restrict__ g1out, unsigned short* __restrict__ valout)
{
  __shared__ __align__(16) unsigned short sA[128*128];
  __shared__ __align__(16) unsigned short sPos[128*128];
  __shared__ float sQ[1024];
  __shared__ int sIdx[128];
  __shared__ float sCtr[24];
  __shared__ float sNbr[384];
  __shared__ float sSum[128];
  __shared__ float sSq[128];
  int tid = threadIdx.x;
  int blk = blockIdx.x;
  int p0 = blk*8;
  int b = p0 >> 13;
  if (tid < 128) sIdx[tid] = idxb[(size_t)p0*16 + tid];
  for (int t=tid; t<1024; t+=256) sQ[t] = qbuf[(size_t)p0*128 + t];
  if (tid < 24) sCtr[tid] = points[(size_t)p0*3 + tid];
  if (tid < 128){ sSum[tid]=0.f; sSq[tid]=0.f; }
  __syncthreads();
  if (tid < 128){
    int nb = sIdx[tid];
    const float* pp = points + (size_t)(b*NPTS + nb)*3;
    sNbr[tid*3+0]=pp[0]; sNbr[tid*3+1]=pp[1]; sNbr[tid*3+2]=pp[2];
  }
  for (int t=tid; t<2048; t+=256){
    int row=t>>4, c=t&15;
    int nb = sIdx[row];
    uint4 v = *(const uint4*)(featb + (size_t)(b*NPTS+nb)*128 + c*8);
    *(uint4*)((char*)sA + swz(row, c*16)) = v;
  }
  __syncthreads();
  int wid = tid>>6, lane = tid&63;
  int r = lane&15, g = lane>>4;
  f32x4 aK[2][8] = {};
  f32x4 aV[2][8] = {};
  {
    const unsigned short* WK = wbf + 16384;
    const unsigned short* WV = wbf + 32768;
    #pragma unroll
    for (int ks=0;ks<4;++ks){
      int k = ks*32 + g*8;
      bf16x8 a0 = ldsA8(sA, wid*32 + r, k);
      bf16x8 a1 = ldsA8(sA, wid*32 + 16 + r, k);
      #pragma unroll
      for (int nt=0;nt<8;++nt){
        bf16x8 bb0 = ldW8(WK, nt*16 + r, k);
        aK[0][nt] = MFMA16(a0, bb0, aK[0][nt]);
        aK[1][nt] = MFMA16(a1, bb0, aK[1][nt]);
        bf16x8 bb1 = ldW8(WV, nt*16 + r, k);
        aV[0][nt] = MFMA16(a0, bb1, aV[0][nt]);
        aV[1][nt] = MFMA16(a1, bb1, aV[1][nt]);
      }
    }
  }
  // pos branch: pos1 -> BN-d -> gelu -> Wd2 -> sPos (bf16, swizzled)
  {
    int row = tid>>1, half = tid&1;
    int p = row>>4;
    float dx = sCtr[p*3+0]-sNbr[row*3+0];
    float dy = sCtr[p*3+1]-sNbr[row*3+1];
    float dz = sCtr[p*3+2]-sNbr[row*3+2];
    float scd0=stats[SD_SC+0], scd1=stats[SD_SC+1], scd2=stats[SD_SC+2];
    float shd0=stats[SD_SH+0], shd1=stats[SD_SH+1], shd2=stats[SD_SH+2];
    float t0 = fmaf(dz,Wd1[2],fmaf(dy,Wd1[1],dx*Wd1[0])) + bd1[0];
    float t1 = fmaf(dz,Wd1[5],fmaf(dy,Wd1[4],dx*Wd1[3])) + bd1[1];
    float t2 = fmaf(dz,Wd1[8],fmaf(dy,Wd1[7],dx*Wd1[6])) + bd1[2];
    float g0 = gelu_f(fmaf(t0,scd0,shd0));
    float g1v = gelu_f(fmaf(t1,scd1,shd1));
    float g2v = gelu_f(fmaf(t2,scd2,shd2));
    #pragma unroll
    for (int c8=0;c8<8;++c8){
      int ch0 = half*64 + c8*8;
      union { uint4 u; unsigned short s[8]; } o;
      #pragma unroll
      for (int u=0;u<8;u++){
        int ch = ch0+u;
        float pv = fmaf(g2v,Wd2[ch*3+2],fmaf(g1v,Wd2[ch*3+1],g0*Wd2[ch*3+0])) + bd2[ch];
        o.s[u] = f2b(pv);
      }
      *(uint4*)((char*)sPos + swz(row, ch0*2)) = o.u;
    }
  }
  __syncthreads();
  // epilogue: gamma1 = q - key + pos ; value = v + pos ; BN-g1 stats
  #pragma unroll
  for (int nt=0;nt<8;++nt){
    int ch = nt*16 + r;
    float bkc = bk[ch], bvc = bv[ch];
    float s_=0.f, qq=0.f;
    #pragma unroll
    for (int mt=0;mt<2;++mt){
      int p = wid*2 + mt;
      float qv = sQ[p*128 + ch];
      #pragma unroll
      for (int rr=0;rr<4;++rr){
        int row = wid*32 + mt*16 + g*4 + rr;
        float pos = b2f(*(const unsigned short*)((const char*)sPos + swz(row, ch*2)));
        float key = aK[mt][nt][rr] + bkc;
        float val = aV[mt][nt][rr] + bvc + pos;
        float gmv = qv - key + pos;
        s_ += gmv; qq = fmaf(gmv,gmv,qq);
        size_t rowg = (size_t)blk*128 + row;
        g1out[rowg*128 + ch] = f2b(gmv);
        valout[rowg*128 + ch] = f2b(val);
      }
    }
    atomicAdd(&sSum[ch], s_);
    atomicAdd(&sSq[ch], qq);
  }
  __syncthreads();
  if (tid < 128){
    atomicAdd(&stats[SG1_SUM+tid], sSum[tid]);
    atomicAdd(&stats[SG1_SSQ+tid], sSq[tid]);
  }
}

__global__ __launch_bounds__(256) void k_g(
    const unsigned short* __restrict__ gin, const unsigned short* __restrict__ W,
    const float* __restrict__ bias, float* __restrict__ stats, int scOff, int shOff,
    unsigned short* __restrict__ gout, int sumOff, int ssqOff)
{
  __shared__ __align__(16) unsigned short sA[128*128];
  __shared__ float sSum[128];
  __shared__ float sSq[128];
  int tid = threadIdx.x;
  size_t row0 = (size_t)blockIdx.x*128;
  if (tid<128){ sSum[tid]=0.f; sSq[tid]=0.f; }
  for (int t=tid; t<2048; t+=256){
    int row=t>>4, c=t&15;
    union { uint4 u; unsigned short s[8]; } iv, ov;
    iv.u = *(const uint4*)(gin + (row0+row)*128 + c*8);
    #pragma unroll
    for (int u=0;u<8;u++){
      int ch = c*8+u;
      float x = b2f(iv.s[u]);
      x = gelu_f(fmaf(x, stats[scOff+ch], stats[shOff+ch]));
      ov.s[u] = f2b(x);
    }
    *(uint4*)((char*)sA + swz(row, c*16)) = ov.u;
  }
  __syncthreads();
  int wid=tid>>6, lane=tid&63;
  int r=lane&15, g=lane>>4;
  f32x4 acc[2][8] = {};
  gemm32(acc, sA, W, wid*32, lane);
  #pragma unroll
  for (int nt=0;nt<8;++nt){
    int ch = nt*16+r;
    float bc = bias[ch];
    float s_=0.f, qq=0.f;
    #pragma unroll
    for (int mt=0;mt<2;++mt){
      #pragma unroll
      for (int rr=0;rr<4;++rr){
        int row = wid*32 + mt*16 + g*4 + rr;
        float x = acc[mt][nt][rr] + bc;
        s_ += x; qq = fmaf(x,x,qq);
        gout[(row0+row)*128 + ch] = f2b(x);
      }
    }
    atomicAdd(&sSum[ch], s_); atomicAdd(&sSq[ch], qq);
  }
  __syncthreads();
  if (tid<128){
    atomicAdd(&stats[sumOff+tid], sSum[tid]);
    atomicAdd(&stats[ssqOff+tid], sSq[tid]);
  }
}

__global__ __launch_bounds__(256) void k_out(
    const unsigned short* __restrict__ gin, const unsigned short* __restrict__ W,
    const float* __restrict__ bias, const float* __restrict__ stats, int scOff, int shOff,
    const unsigned short* __restrict__ val, float* __restrict__ outp)
{
  __shared__ __align__(16) unsigned short sA[128*128];
  __shared__ __align__(16) unsigned short sV[128*128];
  int tid=threadIdx.x;
  size_t row0=(size_t)blockIdx.x*128;
  for (int t=tid;t<2048;t+=256){
    int row=t>>4,c=t&15;
    union { uint4 u; unsigned short s[8]; } iv, ov;
    iv.u = *(const uint4*)(gin + (row0+row)*128 + c*8);
    #pragma unroll
    for (int u=0;u<8;u++){
      int ch=c*8+u;
      float x = b2f(iv.s[u]);
      x = gelu_f(fmaf(x, stats[scOff+ch], stats[shOff+ch]));
      ov.s[u]=f2b(x);
    }
    *(uint4*)((char*)sA + swz(row,c*16)) = ov.u;
    uint4 vv = *(const uint4*)(val + (row0+row)*128 + c*8);
    *(uint4*)((char*)sV + swz(row,c*16)) = vv;
  }
  __syncthreads();
  int wid=tid>>6, lane=tid&63;
  int r=lane&15, g=lane>>4;
  f32x4 acc[2][8] = {};
  gemm32(acc, sA, W, wid*32, lane);
  #pragma unroll
  for (int nt=0;nt<8;++nt){
    int ch=nt*16+r; float bc=bias[ch];
    #pragma unroll
    for (int mt=0;mt<2;++mt){
      float g3[4], vv[4];
      #pragma unroll
      for (int rr=0;rr<4;++rr){
        int row=wid*32+mt*16+g*4+rr;
        g3[rr]=acc[mt][nt][rr]+bc;
        vv[rr]=b2f(*(const unsigned short*)((const char*)sV + swz(row, ch*2)));
      }
      float m = fmaxf(fmaxf(g3[0],g3[1]),fmaxf(g3[2],g3[3]));
      m = fmaxf(m, __shfl_xor(m,16));
      m = fmaxf(m, __shfl_xor(m,32));
      float s=0.f, o=0.f;
      #pragma unroll
      for (int rr=0;rr<4;++rr){
        float e = __expf(g3[rr]-m);
        s += e; o = fmaf(e, vv[rr], o);
      }
      s += __shfl_xor(s,16); s += __shfl_xor(s,32);
      o += __shfl_xor(o,16); o += __shfl_xor(o,32);
      if (g==0){
        int p = wid*2+mt;
        outp[((size_t)blockIdx.x*8 + p)*128 + ch] = o/s;
      }
    }
  }
}

extern "C" void kernel_launch(void* const* d_in, const int* in_sizes, int n_in,
                              void* d_out, int out_size, void* d_ws, size_t ws_size,
                              hipStream_t stream)
{
  const float* feats  = (const float*)d_in[0];
  const float* points = (const float*)d_in[1];
  const float* Wq = (const float*)d_in[2];  const float* bq = (const float*)d_in[3];
  const float* Wk = (const float*)d_in[4];  const float* bk = (const float*)d_in[5];
  const float* Wv = (const float*)d_in[6];  const float* bv = (const float*)d_in[7];
  const float* Wd1= (const float*)d_in[8];  const float* bd1= (const float*)d_in[9];
  const float* Wd2= (const float*)d_in[10]; const float* bd2= (const float*)d_in[11];
  const float* Wg1= (const float*)d_in[12]; const float* bg1= (const float*)d_in[13];
  const float* Wg2= (const float*)d_in[14]; const float* bg2= (const float*)d_in[15];
  const float* gd = (const float*)d_in[16]; const float* betad = (const float*)d_in[17];
  const float* gg1= (const float*)d_in[18]; const float* betag1= (const float*)d_in[19];
  const float* gg2= (const float*)d_in[20]; const float* betag2= (const float*)d_in[21];
  float* outp = (float*)d_out;

  char* ws = (char*)d_ws;
  int*    idxb  = (int*)   (ws + 0);               // 1 MB
  float2* pairs = (float2*)(ws + 1048576);         // 8 MB
  float*  stats = (float*) (ws + 9437184);         // 8 KB
  unsigned short* wbf   = (unsigned short*)(ws + 9445376);   // 160 KB
  unsigned short* featb = (unsigned short*)(ws + 9609216);   // 4 MB
  float*  qbuf  = (float*) (ws + 13803520);        // 8 MB
  unsigned short* g1b = (unsigned short*)(ws + 22192128);    // 64 MB
  unsigned short* vab = (unsigned short*)(ws + 89300992);    // 64 MB
  unsigned short* g2b = (unsigned short*)(ws + 156409856);   // 64 MB

  k_prep<<<dim3(8192),dim3(256),0,stream>>>(feats,Wq,Wk,Wv,Wg1,Wg2,wbf,featb,stats);
  k_knn<<<dim3(256),dim3(256),0,stream>>>(points,pairs);
  k_merge<<<dim3(64),dim3(256),0,stream>>>(pairs,idxb,points,Wd1,bd1,stats);
  k_finalize<<<dim3(1),dim3(64),0,stream>>>(stats,SD_SUM,SD_SSQ,gd,betad,SD_SC,SD_SH,3);
  k_q<<<dim3(128),dim3(256),0,stream>>>(featb,wbf,bq,qbuf);
  k_main<<<dim3(2048),dim3(256),0,stream>>>(points,featb,wbf,bk,bv,Wd1,bd1,Wd2,bd2,idxb,qbuf,stats,g1b,vab);
  k_finalize<<<dim3(2),dim3(64),0,stream>>>(stats,SG1_SUM,SG1_SSQ,gg1,betag1,SG1_SC,SG1_SH,128);
  k_g<<<dim3(2048),dim3(256),0,stream>>>(g1b,wbf+49152,bg1,stats,SG1_SC,SG1_SH,g2b,SG2_SUM,SG2_SSQ);
  k_finalize<<<dim3(2),dim3(64),0,stream>>>(stats,SG2_SUM,SG2_SSQ,gg2,betag2,SG2_SC,SG2_SH,128);
  k_out<<<dim3(2048),dim3(256),0,stream>>>(g2b,wbf+65536,bg2,stats,SG2_SC,SG2_SH,vab,outp);
  (void)in_sizes; (void)n_in; (void)out_size; (void)ws_size;
}